// Round 7
// baseline (273.863 us; speedup 1.0000x reference)
//
#include <hip/hip_runtime.h>

typedef __attribute__((ext_vector_type(8))) short short8;
typedef __attribute__((ext_vector_type(4))) short short4_t;
typedef __attribute__((ext_vector_type(4))) float f32x4;
typedef __attribute__((ext_vector_type(2))) unsigned int u32x2;

#define MFMA_B16(a, b, c) __builtin_amdgcn_mfma_f32_16x16x32_bf16((a), (b), (c), 0, 0, 0)

__device__ __forceinline__ unsigned short f2bf(float x) {
    unsigned u = __builtin_bit_cast(unsigned, x);
    u = (u + 0x7FFFu + ((u >> 16) & 1u)) >> 16;
    return (unsigned short)u;
}

__device__ __forceinline__ void load16_lds(const void* g, void* l) {
    __builtin_amdgcn_global_load_lds(
        (const __attribute__((address_space(1))) unsigned int*)g,
        (__attribute__((address_space(3))) unsigned int*)l, 16, 0, 0);
}

// ---------------- multi-tensor fp32 -> bf16 convert (8 elems/thread) --------
__global__ __launch_bounds__(256) void cvt5(
    const float* s0, unsigned short* d0, int n0,
    const float* s1, unsigned short* d1, int n1,
    const float* s2, unsigned short* d2, int n2,
    const float* s3, unsigned short* d3, int n3,
    const float* s4, unsigned short* d4, int n4)
{
    const float* s; unsigned short* d; int n;
    switch (blockIdx.y) {
        case 0:  s = s0; d = d0; n = n0; break;
        case 1:  s = s1; d = d1; n = n1; break;
        case 2:  s = s2; d = d2; n = n2; break;
        case 3:  s = s3; d = d3; n = n3; break;
        default: s = s4; d = d4; n = n4; break;
    }
    const int i = blockIdx.x * 256 + threadIdx.x;
    if (i < n) {
        const float* p = s + (size_t)i * 8;
        f32x4 x0 = *(const f32x4*)p;
        f32x4 x1 = *(const f32x4*)(p + 4);
        short8 r;
#pragma unroll
        for (int j = 0; j < 4; ++j) r[j] = (short)f2bf(x0[j]);
#pragma unroll
        for (int j = 0; j < 4; ++j) r[j + 4] = (short)f2bf(x1[j]);
        *(short8*)(d + (size_t)i * 8) = r;
    }
}

// ------- NT GEMM: 256x256 tile, 8 waves, counted-vmcnt 2-barrier pipeline ---
// Round-6 post-mortem: gemm time ~155us for 34.4 GFLOP (~220 TF). The 128^2
// tile's 16 MFMA : 8 ds_read : 4 stage per K-step plus a vmcnt(0)-draining
// barrier is the m97-structure ceiling. This kernel: 256^2 tile (32 MFMA : 12
// ds_read per wave per K-step), and the barrier no longer drains the staging
// queue: per K-step {STAGE(next); vmcnt(4) = own CURRENT-tile loads done,
// next tile's 4 stay in flight; s_barrier; ds_read+MFMA; s_barrier}. The
// second barrier orders reads-of-buf before the next overwrite (2 buffers =
// exactly 64 KB LDS). asm memory-fences at each barrier edge stop the
// compiler from moving ds_reads across raw s_barrier (rule 18).
// LDS staging is chunk-XOR swizzled: LDS[r][c16] = G[r][c16 ^ (r&3)] (inverse
// applied on the pre-swizzled GLOBAL source; LDS dest stays linear as
// global_load_lds requires) -- breaks the 8-way bank conflict of [row][32]
// short rows on the fragment reads (read chunk = quad ^ (row&3)).
// Mode 1 (V^T) no longer needs an LDS transpose: acc's f32x4 spans 4
// consecutive rows (= 4 consecutive s) at fixed col d, so a packed 8-byte
// store writes V^T[d][s] directly.
struct GemmDesc {
    const unsigned short* A;
    const unsigned short* W;
    const float* bias;
    void* out;
    float scale;
    int mode;   // 0 = bf16 row-major, 1 = V^T per-head [b][h][64][2048], 2 = fp32
};

__global__ __launch_bounds__(512, 2) void gemm256(GemmDesc g0, GemmDesc g1, GemmDesc g2)
{
    constexpr int K = 1024;
    __shared__ short lds[2 * 16384];   // [buf][A 256x32 | W 256x32] = 64 KB

    const GemmDesc g = (blockIdx.z == 0) ? g0 : (blockIdx.z == 1 ? g1 : g2);
    const int t = threadIdx.x;
    const int lane = t & 63, wave = t >> 6;
    const int lanelo = lane & 15, quad = lane >> 4;
    const int wm = wave >> 2, wn = wave & 3;     // 2M x 4N wave grid
    const int bn = blockIdx.x * 256;
    const int bm = blockIdx.y * 256;

    f32x4 acc[8][4] = {};

    // staging: thread t covers row r0 = t>>2 (and r0+128), 16B chunk c = t&3.
    // pre-swizzled global source col: (c ^ (r0&3)) * 8 shorts.
    const int r0 = t >> 2;
    const int scol = ((t & 3) ^ (r0 & 3)) * 8;
    const unsigned short* Ag = g.A + (size_t)(bm + r0) * K + scol;
    const unsigned short* Wg = g.W + (size_t)(bn + r0) * K + scol;
    const int qx = (quad ^ (lanelo & 3)) * 8;   // swizzled read chunk offset

    short* const myA0 = lds + wave * 512;        // wave-uniform LDS dests
    short* const myW0 = lds + 8192 + wave * 512;

#define STAGE256(k0, buf)                                            \
    do {                                                             \
        short* bA_ = myA0 + (buf) * 16384;                           \
        short* bW_ = myW0 + (buf) * 16384;                           \
        load16_lds(Ag + (k0), bA_);                                  \
        load16_lds(Ag + (size_t)128 * K + (k0), bA_ + 4096);         \
        load16_lds(Wg + (k0), bW_);                                  \
        load16_lds(Wg + (size_t)128 * K + (k0), bW_ + 4096);         \
    } while (0)

#define COMPUTE256(buf)                                              \
    do {                                                             \
        const short* bA = lds + (buf) * 16384;                       \
        const short* bW = bA + 8192;                                 \
        short8 af[8], wf[4];                                         \
        _Pragma("unroll")                                            \
        for (int mt = 0; mt < 8; ++mt)                               \
            af[mt] = *(const short8*)&bA[(wm * 128 + mt * 16 + lanelo) * 32 + qx]; \
        _Pragma("unroll")                                            \
        for (int nt = 0; nt < 4; ++nt)                               \
            wf[nt] = *(const short8*)&bW[(wn * 64 + nt * 16 + lanelo) * 32 + qx]; \
        _Pragma("unroll")                                            \
        for (int mt = 0; mt < 8; ++mt)                               \
            _Pragma("unroll")                                        \
            for (int nt = 0; nt < 4; ++nt)                           \
                acc[mt][nt] = MFMA_B16(af[mt], wf[nt], acc[mt][nt]); \
    } while (0)

    STAGE256(0, 0);
    int cur = 0;
    for (int k0 = 0; k0 < K - 32; k0 += 32) {
        STAGE256(k0 + 32, cur ^ 1);
        asm volatile("s_waitcnt vmcnt(4)" ::: "memory");  // own cur-tile done
        __builtin_amdgcn_s_barrier();                     // all waves' cur done
        asm volatile("" ::: "memory");
        COMPUTE256(cur);
        asm volatile("" ::: "memory");
        __builtin_amdgcn_s_barrier();                     // reads done before overwrite
        cur ^= 1;
    }
    asm volatile("s_waitcnt vmcnt(0)" ::: "memory");      // last tile done
    __builtin_amdgcn_s_barrier();
    asm volatile("" ::: "memory");
    COMPUTE256(cur);

    // ---- epilogue ----
    if (g.mode != 1) {
#pragma unroll
        for (int mt = 0; mt < 8; ++mt) {
#pragma unroll
            for (int nt = 0; nt < 4; ++nt) {
                const int col = bn + wn * 64 + nt * 16 + lanelo;
                const float bs = g.bias[col];
#pragma unroll
                for (int r = 0; r < 4; ++r) {
                    const int row = bm + wm * 128 + mt * 16 + quad * 4 + r;
                    const float val = (acc[mt][nt][r] + bs) * g.scale;
                    if (g.mode == 2)
                        ((float*)g.out)[(size_t)row * K + col] = val;
                    else
                        ((unsigned short*)g.out)[(size_t)row * K + col] = f2bf(val);
                }
            }
        }
    } else {
        // V^T: acc[mt][nt][0..3] = 4 consecutive s at fixed d -> packed 8B store
#pragma unroll
        for (int mt = 0; mt < 8; ++mt) {
            const int row0 = bm + wm * 128 + mt * 16 + quad * 4;
            const int bidx = row0 >> 11;
            const int s    = row0 & 2047;
#pragma unroll
            for (int nt = 0; nt < 4; ++nt) {
                const int d = bn + wn * 64 + nt * 16 + lanelo;
                const float bs = g.bias[d];
                u32x2 pk;
                pk[0] = (unsigned)f2bf(acc[mt][nt][0] + bs) |
                        ((unsigned)f2bf(acc[mt][nt][1] + bs) << 16);
                pk[1] = (unsigned)f2bf(acc[mt][nt][2] + bs) |
                        ((unsigned)f2bf(acc[mt][nt][3] + bs) << 16);
                unsigned short* dst = (unsigned short*)g.out +
                    ((size_t)((bidx * 16 + (d >> 6)) * 64 + (d & 63))) * 2048 + s;
                *(u32x2*)dst = pk;
            }
        }
    }
#undef STAGE256
#undef COMPUTE256
}

// ------- flash attention: Q-split 4-wave, LDS K/V, swapped QK^T softmax ----
// (unchanged from round 6: 81 us, verified)
__global__ __launch_bounds__(256) void attn_flash(
    const unsigned short* __restrict__ Qs,
    const unsigned short* __restrict__ Ks,
    const unsigned short* __restrict__ Vt,
    unsigned short* __restrict__ Op)
{
    constexpr int S = 2048, D = 1024;
    __shared__ short Kb[2][64 * 64];   // [buf][key][d-swizzled]  8 KB each
    __shared__ short Vb[2][64 * 64];   // [buf][d][key-swizzled]  8 KB each
    __shared__ short Pl[4][32 * 72];   // per-wave P tile [32 q][64 key]

    const int tid    = threadIdx.x;
    const int lane   = tid & 63;
    const int wave   = tid >> 6;          // Q-split slot 0..3
    const int lanelo = lane & 15;
    const int quad   = lane >> 4;
    const int qt = blockIdx.x;            // 0..15 (128 q-rows per block)
    const int bh = blockIdx.y;            // 0..31
    const int b  = bh >> 4;
    const int h  = bh & 15;
    const size_t base = (size_t)b * S * D + (size_t)h * 64;
    const unsigned short* Vh = Vt + (size_t)bh * 64 * S;
    short* Plw = Pl[wave];
    const int qrow0 = qt * 128 + wave * 32;

    short8 aq[2][2];
#pragma unroll
    for (int mt = 0; mt < 2; ++mt)
#pragma unroll
        for (int ks = 0; ks < 2; ++ks)
            aq[mt][ks] = *(const short8*)(Qs + base +
                (size_t)(qrow0 + mt * 16 + lanelo) * D + ks * 32 + quad * 8);

    f32x4 oacc[2][4] = {};
    float lac[2] = {0.0f, 0.0f};          // per-lane partial l for q=mt*16+lanelo

    const int lr = lane >> 3;
    const int lc = (((lane & 7) ^ lr) * 8);
    const unsigned short* kg = Ks + base + (size_t)(wave * 16 + lr) * D + lc;
    const unsigned short* vg = Vh + (size_t)(wave * 16 + lr) * S + lc;

#pragma unroll
    for (int i = 0; i < 2; ++i) {
        load16_lds(kg + (size_t)(i * 8) * D, &Kb[0][(wave * 2 + i) * 512]);
        load16_lds(vg + (size_t)(i * 8) * S, &Vb[0][(wave * 2 + i) * 512]);
    }
    __syncthreads();

    int cur = 0;
    for (int kt = 0; kt < 32; ++kt) {
        if (kt < 31) {
            const unsigned short* kgn = kg + (size_t)(kt + 1) * 64 * D;
            const unsigned short* vgn = vg + (kt + 1) * 64;
#pragma unroll
            for (int i = 0; i < 2; ++i) {
                load16_lds(kgn + (size_t)(i * 8) * D, &Kb[cur ^ 1][(wave * 2 + i) * 512]);
                load16_lds(vgn + (size_t)(i * 8) * S, &Vb[cur ^ 1][(wave * 2 + i) * 512]);
            }
        }

        short8 kfr[2][4];
#pragma unroll
        for (int ks = 0; ks < 2; ++ks)
#pragma unroll
            for (int nk = 0; nk < 4; ++nk) {
                const int k = nk * 16 + lanelo;
                kfr[ks][nk] = *(const short8*)&Kb[cur][k * 64 +
                    ((ks * 32 + quad * 8) ^ ((k & 7) << 3))];
            }

        f32x4 sv[2][4] = {};
        __builtin_amdgcn_s_setprio(1);
#pragma unroll
        for (int ks = 0; ks < 2; ++ks)
#pragma unroll
            for (int mt = 0; mt < 2; ++mt)
#pragma unroll
                for (int nt = 0; nt < 4; ++nt)
                    sv[mt][nt] = MFMA_B16(kfr[ks][nt], aq[mt][ks], sv[mt][nt]);
        __builtin_amdgcn_s_setprio(0);

#pragma unroll
        for (int mt = 0; mt < 2; ++mt)
#pragma unroll
            for (int nt = 0; nt < 4; ++nt) {
                unsigned u[4];
#pragma unroll
                for (int r = 0; r < 4; ++r) {
                    const float p = exp2f(sv[mt][nt][r]);
                    const unsigned tr = __builtin_bit_cast(unsigned, p) & 0xFFFF0000u;
                    lac[mt] += __builtin_bit_cast(float, tr);
                    u[r] = tr;
                }
                u32x2 pk;
                pk[0] = __builtin_amdgcn_perm(u[1], u[0], 0x07060302u);
                pk[1] = __builtin_amdgcn_perm(u[3], u[2], 0x07060302u);
                *(u32x2*)&Plw[(mt * 16 + lanelo) * 72 + nt * 16 + quad * 4] = pk;
            }

        __builtin_amdgcn_wave_barrier();

        __builtin_amdgcn_s_setprio(1);
#pragma unroll
        for (int ks = 0; ks < 2; ++ks) {
            short8 vfr[4];
#pragma unroll
            for (int nt = 0; nt < 4; ++nt) {
                const int d = nt * 16 + lanelo;
                vfr[nt] = *(const short8*)&Vb[cur][d * 64 +
                    ((ks * 32 + quad * 8) ^ ((d & 7) << 3))];
            }
            short8 ap[2];
#pragma unroll
            for (int mt = 0; mt < 2; ++mt)
                ap[mt] = *(const short8*)&Plw[(mt * 16 + lanelo) * 72 + ks * 32 + quad * 8];
#pragma unroll
            for (int mt = 0; mt < 2; ++mt)
#pragma unroll
                for (int nt = 0; nt < 4; ++nt)
                    oacc[mt][nt] = MFMA_B16(ap[mt], vfr[nt], oacc[mt][nt]);
        }
        __builtin_amdgcn_s_setprio(0);

        if (kt < 31) {
            __syncthreads();
            cur ^= 1;
        }
    }

    float lfull[2];
#pragma unroll
    for (int mt = 0; mt < 2; ++mt) {
        float l = lac[mt];
        l += __shfl_xor(l, 16);
        l += __shfl_xor(l, 32);
        lfull[mt] = l;
    }

#pragma unroll
    for (int mt = 0; mt < 2; ++mt)
#pragma unroll
        for (int r = 0; r < 4; ++r) {
            const float inv = 1.0f / __shfl(lfull[mt], quad * 4 + r);
            const int row = qrow0 + mt * 16 + quad * 4 + r;
#pragma unroll
            for (int nt = 0; nt < 4; ++nt)
                Op[base + (size_t)row * D + nt * 16 + lanelo] = f2bf(oacc[mt][nt][r] * inv);
        }
}

extern "C" void kernel_launch(void* const* d_in, const int* in_sizes, int n_in,
                              void* d_out, int out_size, void* d_ws, size_t ws_size,
                              hipStream_t stream) {
    const float* q   = (const float*)d_in[0];
    const float* k   = (const float*)d_in[1];
    const float* v   = (const float*)d_in[2];
    const float* W_q = (const float*)d_in[3];
    const float* b_q = (const float*)d_in[4];
    const float* W_k = (const float*)d_in[5];
    const float* b_k = (const float*)d_in[6];
    const float* W_v = (const float*)d_in[7];
    const float* b_v = (const float*)d_in[8];
    const float* W_o = (const float*)d_in[9];
    const float* b_o = (const float*)d_in[10];

    constexpr size_t M4 = (size_t)4 * 1024 * 1024;
    constexpr size_t M1 = (size_t)1024 * 1024;

    unsigned short* ob   = (unsigned short*)d_out;
    unsigned short* qb16 = ob;                 // [0,4M)
    unsigned short* wq16 = ob + M4;            // [4M,5M)
    unsigned short* wk16 = ob + M4 + M1;       // [5M,6M)
    unsigned short* wv16 = ob + M4 + 2 * M1;   // [6M,7M)
    unsigned short* d0   = (unsigned short*)d_in[0];
    unsigned short* d1   = (unsigned short*)d_in[1];
    unsigned short* d2   = (unsigned short*)d_in[2];
    unsigned short* kb16 = d0;                 // k bf16 (q fp32 dead after cvtA)
    unsigned short* vb16 = d0 + M4;            // v bf16
    unsigned short* wo16 = d0;                 // W_o bf16 (over kb16, after QKV gemm)
    unsigned short* Qst  = d1;                 // Q stage
    unsigned short* Kst  = d1 + M4;            // K stage
    unsigned short* Vts  = d2;                 // V^T stage
    unsigned short* Ob16 = d2 + M4;            // O stage
    float*          outp = (float*)d_out;

    const dim3 blk(256, 1, 1);
    const int n4 = (int)(M4 / 8), n1 = (int)(M1 / 8);
    const float QSCALE = 0.18033688f;    // 0.125 * log2(e)

    cvt5<<<dim3(2048, 4, 1), blk, 0, stream>>>(
        q, qb16, n4,  W_q, wq16, n1,  W_k, wk16, n1,  W_v, wv16, n1,
        (const float*)nullptr, (unsigned short*)nullptr, 0);
    cvt5<<<dim3(2048, 2, 1), blk, 0, stream>>>(
        k, kb16, n4,  v, vb16, n4, nullptr, nullptr, 0,
        nullptr, nullptr, 0, nullptr, nullptr, 0);
    {
        GemmDesc gq{qb16, wq16, b_q, Qst, QSCALE, 0};
        GemmDesc gk{kb16, wk16, b_k, Kst, 1.0f, 0};
        GemmDesc gv{vb16, wv16, b_v, Vts, 1.0f, 1};
        gemm256<<<dim3(4, 16, 3), dim3(512, 1, 1), 0, stream>>>(gq, gk, gv);
    }
    cvt5<<<dim3(512, 1, 1), blk, 0, stream>>>(
        W_o, wo16, n1, nullptr, nullptr, 0, nullptr, nullptr, 0,
        nullptr, nullptr, 0, nullptr, nullptr, 0);
    attn_flash<<<dim3(16, 32, 1), blk, 0, stream>>>(Qst, Kst, Vts, Ob16);
    {
        GemmDesc go{Ob16, wo16, b_o, outp, 1.0f, 2};
        gemm256<<<dim3(4, 16, 1), dim3(512, 1, 1), 0, stream>>>(go, go, go);
    }
}

// Round 8
// 255.548 us; speedup vs baseline: 1.0717x; 1.0717x over previous
//
#include <hip/hip_runtime.h>

typedef __attribute__((ext_vector_type(8))) short short8;
typedef __attribute__((ext_vector_type(4))) short short4_t;
typedef __attribute__((ext_vector_type(4))) float f32x4;
typedef __attribute__((ext_vector_type(2))) unsigned int u32x2;

#define MFMA_B16(a, b, c) __builtin_amdgcn_mfma_f32_16x16x32_bf16((a), (b), (c), 0, 0, 0)

__device__ __forceinline__ unsigned short f2bf(float x) {
    unsigned u = __builtin_bit_cast(unsigned, x);
    u = (u + 0x7FFFu + ((u >> 16) & 1u)) >> 16;
    return (unsigned short)u;
}

__device__ __forceinline__ void load16_lds(const void* g, void* l) {
    __builtin_amdgcn_global_load_lds(
        (const __attribute__((address_space(1))) unsigned int*)g,
        (__attribute__((address_space(3))) unsigned int*)l, 16, 0, 0);
}

// ---------------- multi-tensor fp32 -> bf16 convert (8 elems/thread) --------
__global__ __launch_bounds__(256) void cvt5(
    const float* s0, unsigned short* d0, int n0,
    const float* s1, unsigned short* d1, int n1,
    const float* s2, unsigned short* d2, int n2,
    const float* s3, unsigned short* d3, int n3,
    const float* s4, unsigned short* d4, int n4)
{
    const float* s; unsigned short* d; int n;
    switch (blockIdx.y) {
        case 0:  s = s0; d = d0; n = n0; break;
        case 1:  s = s1; d = d1; n = n1; break;
        case 2:  s = s2; d = d2; n = n2; break;
        case 3:  s = s3; d = d3; n = n3; break;
        default: s = s4; d = d4; n = n4; break;
    }
    const int i = blockIdx.x * 256 + threadIdx.x;
    if (i < n) {
        const float* p = s + (size_t)i * 8;
        f32x4 x0 = *(const f32x4*)p;
        f32x4 x1 = *(const f32x4*)(p + 4);
        short8 r;
#pragma unroll
        for (int j = 0; j < 4; ++j) r[j] = (short)f2bf(x0[j]);
#pragma unroll
        for (int j = 0; j < 4; ++j) r[j + 4] = (short)f2bf(x1[j]);
        *(short8*)(d + (size_t)i * 8) = r;
    }
}

// -- NT GEMM: 128x128 tile, 3-deep ring buffer, counted-vmcnt single barrier -
// Round-7 post-mortem: 256^2 tile shrank the grid to 64 blocks for O-proj
// (75% of 256 CUs idle) -- tile must fit N=1024. Back to 128^2 (grid 256-768)
// and graft the counted-vmcnt protocol (T4) onto it:
//   per K-step: vmcnt(4)  [own tile-k loads done; tile-k+1's 4 stay in
//               flight]; s_barrier  [all waves' tile-k data present AND all
//               waves finished computing tile k-1]; STAGE(k+2) [overwrites
//               tile k-1's buffer -- safe by the barrier]; 16 MFMA.
// One barrier per K-step, vmcnt NEVER drained to 0 in steady state; each
// tile's loads get ~2 full compute phases to land (3-deep ring), vs the
// round-6 2-phase version whose vmcnt(0)-draining __syncthreads exposed
// (load latency - one compute phase) every K-step.
// Memory layout, fragment reads, epilogues identical to the verified round-6
// kernel. Mode-1 regains an explicit __syncthreads before the Lt transpose
// (the loop no longer ends in a barrier; Lt aliases the staging buffers).
struct GemmDesc {
    const unsigned short* A;
    const unsigned short* W;
    const float* bias;
    void* out;
    float scale;
    int mode;   // 0 = bf16 row-major, 1 = V^T per-head [b][h][64][2048], 2 = fp32
};

__global__ __launch_bounds__(256) void gemm128(GemmDesc g0, GemmDesc g1, GemmDesc g2)
{
    constexpr int K = 1024;
    __shared__ union {
        struct { short A[3][128 * 32]; short W[3][128 * 32]; } st;  // 48 KB
        short Lt[128 * 136];                                        // 34.8 KB
    } sm;

    const GemmDesc g = (blockIdx.z == 0) ? g0 : (blockIdx.z == 1 ? g1 : g2);
    const int t = threadIdx.x;
    const int lane = t & 63, wave = t >> 6;
    const int lanelo = lane & 15, quad = lane >> 4;
    const int wm = wave >> 1, wn = wave & 1;
    const int bn = blockIdx.x * 128;
    const int bm = blockIdx.y * 128;

    f32x4 acc[4][4] = {};

    const int r0 = t >> 2, c0 = (t & 3) * 8;
    const unsigned short* Ag = g.A + (size_t)(bm + r0) * K + c0;
    const unsigned short* Wg = g.W + (size_t)(bn + r0) * K + c0;

#define STAGE128(k0, buf)                                             \
    do {                                                              \
        short* la_ = sm.st.A[(buf)] + wave * 512;                     \
        short* lw_ = sm.st.W[(buf)] + wave * 512;                     \
        load16_lds(Ag + (k0), la_);                                   \
        load16_lds(Ag + (size_t)64 * K + (k0), la_ + 2048);           \
        load16_lds(Wg + (k0), lw_);                                   \
        load16_lds(Wg + (size_t)64 * K + (k0), lw_ + 2048);           \
    } while (0)

    // prologue: tiles 0 and 1 in flight
    STAGE128(0, 0);
    STAGE128(32, 1);

    int cur = 0;
    for (int k0 = 0; k0 < K; k0 += 32) {
        if (k0 + 32 < K) {
            asm volatile("s_waitcnt vmcnt(4)" ::: "memory");  // tile k0 landed
        } else {
            asm volatile("s_waitcnt vmcnt(0)" ::: "memory");  // last tile
        }
        __builtin_amdgcn_s_barrier();        // all waves: tile-k0 data present,
        asm volatile("" ::: "memory");       // tile-(k0-32) compute finished

        if (k0 + 64 < K) {
            const int nb = (cur + 2 >= 3) ? cur - 1 : cur + 2;
            STAGE128(k0 + 64, nb);           // overwrites tile k0-32 (safe)
        }

        short8 af[4], wf[4];
#pragma unroll
        for (int mt = 0; mt < 4; ++mt)
            af[mt] = *(const short8*)&sm.st.A[cur][(wm * 64 + mt * 16 + lanelo) * 32 + quad * 8];
#pragma unroll
        for (int nt = 0; nt < 4; ++nt)
            wf[nt] = *(const short8*)&sm.st.W[cur][(wn * 64 + nt * 16 + lanelo) * 32 + quad * 8];
#pragma unroll
        for (int mt = 0; mt < 4; ++mt)
#pragma unroll
            for (int nt = 0; nt < 4; ++nt)
                acc[mt][nt] = MFMA_B16(af[mt], wf[nt], acc[mt][nt]);

        asm volatile("" ::: "memory");
        cur = (cur + 1 == 3) ? 0 : cur + 1;
    }
#undef STAGE128

    if (g.mode != 1) {
#pragma unroll
        for (int mt = 0; mt < 4; ++mt) {
#pragma unroll
            for (int nt = 0; nt < 4; ++nt) {
                const int col = bn + wn * 64 + nt * 16 + lanelo;
                const float bs = g.bias[col];
#pragma unroll
                for (int r = 0; r < 4; ++r) {
                    const int row = bm + wm * 64 + mt * 16 + quad * 4 + r;
                    const float val = (acc[mt][nt][r] + bs) * g.scale;
                    if (g.mode == 2)
                        ((float*)g.out)[(size_t)row * K + col] = val;
                    else
                        ((unsigned short*)g.out)[(size_t)row * K + col] = f2bf(val);
                }
            }
        }
    } else {
        __syncthreads();   // staging reads done before Lt (aliases st) is written
#pragma unroll
        for (int mt = 0; mt < 4; ++mt) {
#pragma unroll
            for (int nt = 0; nt < 4; ++nt) {
                const int nl = wn * 64 + nt * 16 + lanelo;
                const float bs = g.bias[bn + nl];
                short4_t pk;
#pragma unroll
                for (int r = 0; r < 4; ++r) pk[r] = (short)f2bf(acc[mt][nt][r] + bs);
                *(short4_t*)&sm.Lt[nl * 136 + wm * 64 + mt * 16 + quad * 4] = pk;
            }
        }
        __syncthreads();
        const int dl = t >> 1;
        const int sb = (t & 1) * 64;
        const int bb = bm >> 11;
        const int s0 = bm & 2047;
        const int hb = bb * 16 + ((bn + dl) >> 6);
        const int dd = (bn + dl) & 63;
        unsigned short* dst = (unsigned short*)g.out +
            ((size_t)hb * 64 + dd) * 2048 + s0 + sb;
#pragma unroll
        for (int j = 0; j < 8; ++j)
            *(short8*)(dst + j * 8) = *(const short8*)&sm.Lt[dl * 136 + sb + j * 8];
    }
}

// ------- flash attention: Q-split 4-wave, LDS K/V, swapped QK^T softmax ----
// (unchanged from round 6: 81 us, verified)
__global__ __launch_bounds__(256) void attn_flash(
    const unsigned short* __restrict__ Qs,
    const unsigned short* __restrict__ Ks,
    const unsigned short* __restrict__ Vt,
    unsigned short* __restrict__ Op)
{
    constexpr int S = 2048, D = 1024;
    __shared__ short Kb[2][64 * 64];   // [buf][key][d-swizzled]  8 KB each
    __shared__ short Vb[2][64 * 64];   // [buf][d][key-swizzled]  8 KB each
    __shared__ short Pl[4][32 * 72];   // per-wave P tile [32 q][64 key]

    const int tid    = threadIdx.x;
    const int lane   = tid & 63;
    const int wave   = tid >> 6;          // Q-split slot 0..3
    const int lanelo = lane & 15;
    const int quad   = lane >> 4;
    const int qt = blockIdx.x;            // 0..15 (128 q-rows per block)
    const int bh = blockIdx.y;            // 0..31
    const int b  = bh >> 4;
    const int h  = bh & 15;
    const size_t base = (size_t)b * S * D + (size_t)h * 64;
    const unsigned short* Vh = Vt + (size_t)bh * 64 * S;
    short* Plw = Pl[wave];
    const int qrow0 = qt * 128 + wave * 32;

    short8 aq[2][2];
#pragma unroll
    for (int mt = 0; mt < 2; ++mt)
#pragma unroll
        for (int ks = 0; ks < 2; ++ks)
            aq[mt][ks] = *(const short8*)(Qs + base +
                (size_t)(qrow0 + mt * 16 + lanelo) * D + ks * 32 + quad * 8);

    f32x4 oacc[2][4] = {};
    float lac[2] = {0.0f, 0.0f};          // per-lane partial l for q=mt*16+lanelo

    const int lr = lane >> 3;
    const int lc = (((lane & 7) ^ lr) * 8);
    const unsigned short* kg = Ks + base + (size_t)(wave * 16 + lr) * D + lc;
    const unsigned short* vg = Vh + (size_t)(wave * 16 + lr) * S + lc;

#pragma unroll
    for (int i = 0; i < 2; ++i) {
        load16_lds(kg + (size_t)(i * 8) * D, &Kb[0][(wave * 2 + i) * 512]);
        load16_lds(vg + (size_t)(i * 8) * S, &Vb[0][(wave * 2 + i) * 512]);
    }
    __syncthreads();

    int cur = 0;
    for (int kt = 0; kt < 32; ++kt) {
        if (kt < 31) {
            const unsigned short* kgn = kg + (size_t)(kt + 1) * 64 * D;
            const unsigned short* vgn = vg + (kt + 1) * 64;
#pragma unroll
            for (int i = 0; i < 2; ++i) {
                load16_lds(kgn + (size_t)(i * 8) * D, &Kb[cur ^ 1][(wave * 2 + i) * 512]);
                load16_lds(vgn + (size_t)(i * 8) * S, &Vb[cur ^ 1][(wave * 2 + i) * 512]);
            }
        }

        short8 kfr[2][4];
#pragma unroll
        for (int ks = 0; ks < 2; ++ks)
#pragma unroll
            for (int nk = 0; nk < 4; ++nk) {
                const int k = nk * 16 + lanelo;
                kfr[ks][nk] = *(const short8*)&Kb[cur][k * 64 +
                    ((ks * 32 + quad * 8) ^ ((k & 7) << 3))];
            }

        f32x4 sv[2][4] = {};
        __builtin_amdgcn_s_setprio(1);
#pragma unroll
        for (int ks = 0; ks < 2; ++ks)
#pragma unroll
            for (int mt = 0; mt < 2; ++mt)
#pragma unroll
                for (int nt = 0; nt < 4; ++nt)
                    sv[mt][nt] = MFMA_B16(kfr[ks][nt], aq[mt][ks], sv[mt][nt]);
        __builtin_amdgcn_s_setprio(0);

#pragma unroll
        for (int mt = 0; mt < 2; ++mt)
#pragma unroll
            for (int nt = 0; nt < 4; ++nt) {
                unsigned u[4];
#pragma unroll
                for (int r = 0; r < 4; ++r) {
                    const float p = exp2f(sv[mt][nt][r]);
                    const unsigned tr = __builtin_bit_cast(unsigned, p) & 0xFFFF0000u;
                    lac[mt] += __builtin_bit_cast(float, tr);
                    u[r] = tr;
                }
                u32x2 pk;
                pk[0] = __builtin_amdgcn_perm(u[1], u[0], 0x07060302u);
                pk[1] = __builtin_amdgcn_perm(u[3], u[2], 0x07060302u);
                *(u32x2*)&Plw[(mt * 16 + lanelo) * 72 + nt * 16 + quad * 4] = pk;
            }

        __builtin_amdgcn_wave_barrier();

        __builtin_amdgcn_s_setprio(1);
#pragma unroll
        for (int ks = 0; ks < 2; ++ks) {
            short8 vfr[4];
#pragma unroll
            for (int nt = 0; nt < 4; ++nt) {
                const int d = nt * 16 + lanelo;
                vfr[nt] = *(const short8*)&Vb[cur][d * 64 +
                    ((ks * 32 + quad * 8) ^ ((d & 7) << 3))];
            }
            short8 ap[2];
#pragma unroll
            for (int mt = 0; mt < 2; ++mt)
                ap[mt] = *(const short8*)&Plw[(mt * 16 + lanelo) * 72 + ks * 32 + quad * 8];
#pragma unroll
            for (int mt = 0; mt < 2; ++mt)
#pragma unroll
                for (int nt = 0; nt < 4; ++nt)
                    oacc[mt][nt] = MFMA_B16(ap[mt], vfr[nt], oacc[mt][nt]);
        }
        __builtin_amdgcn_s_setprio(0);

        if (kt < 31) {
            __syncthreads();
            cur ^= 1;
        }
    }

    float lfull[2];
#pragma unroll
    for (int mt = 0; mt < 2; ++mt) {
        float l = lac[mt];
        l += __shfl_xor(l, 16);
        l += __shfl_xor(l, 32);
        lfull[mt] = l;
    }

#pragma unroll
    for (int mt = 0; mt < 2; ++mt)
#pragma unroll
        for (int r = 0; r < 4; ++r) {
            const float inv = 1.0f / __shfl(lfull[mt], quad * 4 + r);
            const int row = qrow0 + mt * 16 + quad * 4 + r;
#pragma unroll
            for (int nt = 0; nt < 4; ++nt)
                Op[base + (size_t)row * D + nt * 16 + lanelo] = f2bf(oacc[nt == 0 ? mt : mt][nt][r] * inv);
        }
}

extern "C" void kernel_launch(void* const* d_in, const int* in_sizes, int n_in,
                              void* d_out, int out_size, void* d_ws, size_t ws_size,
                              hipStream_t stream) {
    const float* q   = (const float*)d_in[0];
    const float* k   = (const float*)d_in[1];
    const float* v   = (const float*)d_in[2];
    const float* W_q = (const float*)d_in[3];
    const float* b_q = (const float*)d_in[4];
    const float* W_k = (const float*)d_in[5];
    const float* b_k = (const float*)d_in[6];
    const float* W_v = (const float*)d_in[7];
    const float* b_v = (const float*)d_in[8];
    const float* W_o = (const float*)d_in[9];
    const float* b_o = (const float*)d_in[10];

    constexpr size_t M4 = (size_t)4 * 1024 * 1024;
    constexpr size_t M1 = (size_t)1024 * 1024;

    unsigned short* ob   = (unsigned short*)d_out;
    unsigned short* qb16 = ob;                 // [0,4M)
    unsigned short* wq16 = ob + M4;            // [4M,5M)
    unsigned short* wk16 = ob + M4 + M1;       // [5M,6M)
    unsigned short* wv16 = ob + M4 + 2 * M1;   // [6M,7M)
    unsigned short* d0   = (unsigned short*)d_in[0];
    unsigned short* d1   = (unsigned short*)d_in[1];
    unsigned short* d2   = (unsigned short*)d_in[2];
    unsigned short* kb16 = d0;                 // k bf16 (q fp32 dead after cvtA)
    unsigned short* vb16 = d0 + M4;            // v bf16
    unsigned short* wo16 = d0;                 // W_o bf16 (over kb16, after QKV gemm)
    unsigned short* Qst  = d1;                 // Q stage
    unsigned short* Kst  = d1 + M4;            // K stage
    unsigned short* Vts  = d2;                 // V^T stage
    unsigned short* Ob16 = d2 + M4;            // O stage
    float*          outp = (float*)d_out;

    const dim3 blk(256, 1, 1);
    const int n4 = (int)(M4 / 8), n1 = (int)(M1 / 8);
    const float QSCALE = 0.18033688f;    // 0.125 * log2(e)

    cvt5<<<dim3(2048, 4, 1), blk, 0, stream>>>(
        q, qb16, n4,  W_q, wq16, n1,  W_k, wk16, n1,  W_v, wv16, n1,
        (const float*)nullptr, (unsigned short*)nullptr, 0);
    cvt5<<<dim3(2048, 2, 1), blk, 0, stream>>>(
        k, kb16, n4,  v, vb16, n4, nullptr, nullptr, 0,
        nullptr, nullptr, 0, nullptr, nullptr, 0);
    {
        GemmDesc gq{qb16, wq16, b_q, Qst, QSCALE, 0};
        GemmDesc gk{kb16, wk16, b_k, Kst, 1.0f, 0};
        GemmDesc gv{vb16, wv16, b_v, Vts, 1.0f, 1};
        gemm128<<<dim3(8, 32, 3), blk, 0, stream>>>(gq, gk, gv);
    }
    cvt5<<<dim3(512, 1, 1), blk, 0, stream>>>(
        W_o, wo16, n1, nullptr, nullptr, 0, nullptr, nullptr, 0,
        nullptr, nullptr, 0, nullptr, nullptr, 0);
    attn_flash<<<dim3(16, 32, 1), blk, 0, stream>>>(Qst, Kst, Vts, Ob16);
    {
        GemmDesc go{Ob16, wo16, b_o, outp, 1.0f, 2};
        gemm128<<<dim3(8, 32, 1), blk, 0, stream>>>(go, go, go);
    }
}

// Round 9
// 250.492 us; speedup vs baseline: 1.0933x; 1.0202x over previous
//
#include <hip/hip_runtime.h>

typedef __attribute__((ext_vector_type(8))) short short8;
typedef __attribute__((ext_vector_type(4))) short short4_t;
typedef __attribute__((ext_vector_type(4))) float f32x4;
typedef __attribute__((ext_vector_type(2))) unsigned int u32x2;

#define MFMA_B16(a, b, c) __builtin_amdgcn_mfma_f32_16x16x32_bf16((a), (b), (c), 0, 0, 0)

__device__ __forceinline__ unsigned short f2bf(float x) {
    unsigned u = __builtin_bit_cast(unsigned, x);
    u = (u + 0x7FFFu + ((u >> 16) & 1u)) >> 16;
    return (unsigned short)u;
}

__device__ __forceinline__ void load16_lds(const void* g, void* l) {
    __builtin_amdgcn_global_load_lds(
        (const __attribute__((address_space(1))) unsigned int*)g,
        (__attribute__((address_space(3))) unsigned int*)l, 16, 0, 0);
}

// ---------------- multi-tensor fp32 -> bf16 convert (8 elems/thread) --------
__global__ __launch_bounds__(256) void cvt5(
    const float* s0, unsigned short* d0, int n0,
    const float* s1, unsigned short* d1, int n1,
    const float* s2, unsigned short* d2, int n2,
    const float* s3, unsigned short* d3, int n3,
    const float* s4, unsigned short* d4, int n4)
{
    const float* s; unsigned short* d; int n;
    switch (blockIdx.y) {
        case 0:  s = s0; d = d0; n = n0; break;
        case 1:  s = s1; d = d1; n = n1; break;
        case 2:  s = s2; d = d2; n = n2; break;
        case 3:  s = s3; d = d3; n = n3; break;
        default: s = s4; d = d4; n = n4; break;
    }
    const int i = blockIdx.x * 256 + threadIdx.x;
    if (i < n) {
        const float* p = s + (size_t)i * 8;
        f32x4 x0 = *(const f32x4*)p;
        f32x4 x1 = *(const f32x4*)(p + 4);
        short8 r;
#pragma unroll
        for (int j = 0; j < 4; ++j) r[j] = (short)f2bf(x0[j]);
#pragma unroll
        for (int j = 0; j < 4; ++j) r[j + 4] = (short)f2bf(x1[j]);
        *(short8*)(d + (size_t)i * 8) = r;
    }
}

// -- NT GEMM: 128x128 tile, 3-ring counted-vmcnt, XCD-chunked block remap ----
// Round-8 post-mortem: scheduling grafts are null (m131-m140 pattern); the
// ~3x per-K-step stall is L3-class load latency. Default dispatch round-
// robins XCDs, so each XCD's 4MB L2 sees 3 W matrices (6MB) + 3 interleaved
// A streams -> misses. XCD-chunked remap (bijective, nwg%8==0): physical
// block p (on XCD p%8) takes work (p%8)*(nwg/8)+p/8, giving each XCD a
// contiguous (z,bm)-slab: ONE W (2MB, re-read 12x -> L2-resident) + a 3MB
// A-slab. Also fixes O-proj (256 blocks = 1/CU, stalls fully exposed ->
// L2-hit latency halves the exposure).
struct GemmDesc {
    const unsigned short* A;
    const unsigned short* W;
    const float* bias;
    void* out;
    float scale;
    int mode;   // 0 = bf16 row-major, 1 = V^T per-head [b][h][64][2048], 2 = fp32
};

__global__ __launch_bounds__(256) void gemm128(GemmDesc g0, GemmDesc g1, GemmDesc g2)
{
    constexpr int K = 1024;
    __shared__ union {
        struct { short A[3][128 * 32]; short W[3][128 * 32]; } st;  // 48 KB
        short Lt[128 * 136];                                        // 34.8 KB
    } sm;

    // XCD-chunked bijective remap (requires nwg % 8 == 0; 768 and 256 both ok)
    const unsigned nwg = gridDim.x * gridDim.y * gridDim.z;
    const unsigned lin = blockIdx.x + gridDim.x * (blockIdx.y + gridDim.y * blockIdx.z);
    const unsigned wl  = (lin & 7u) * (nwg >> 3) + (lin >> 3);
    const unsigned pxy = gridDim.x * gridDim.y;
    const unsigned bz  = wl / pxy;
    const unsigned rm  = wl - bz * pxy;
    const unsigned by  = rm / gridDim.x;
    const unsigned bx  = rm - by * gridDim.x;

    const GemmDesc g = (bz == 0) ? g0 : (bz == 1 ? g1 : g2);
    const int t = threadIdx.x;
    const int lane = t & 63, wave = t >> 6;
    const int lanelo = lane & 15, quad = lane >> 4;
    const int wm = wave >> 1, wn = wave & 1;
    const int bn = bx * 128;
    const int bm = by * 128;

    f32x4 acc[4][4] = {};

    const int r0 = t >> 2, c0 = (t & 3) * 8;
    const unsigned short* Ag = g.A + (size_t)(bm + r0) * K + c0;
    const unsigned short* Wg = g.W + (size_t)(bn + r0) * K + c0;

#define STAGE128(k0, buf)                                             \
    do {                                                              \
        short* la_ = sm.st.A[(buf)] + wave * 512;                     \
        short* lw_ = sm.st.W[(buf)] + wave * 512;                     \
        load16_lds(Ag + (k0), la_);                                   \
        load16_lds(Ag + (size_t)64 * K + (k0), la_ + 2048);           \
        load16_lds(Wg + (k0), lw_);                                   \
        load16_lds(Wg + (size_t)64 * K + (k0), lw_ + 2048);           \
    } while (0)

    // prologue: tiles 0 and 1 in flight
    STAGE128(0, 0);
    STAGE128(32, 1);

    int cur = 0;
    for (int k0 = 0; k0 < K; k0 += 32) {
        if (k0 + 32 < K) {
            asm volatile("s_waitcnt vmcnt(4)" ::: "memory");  // tile k0 landed
        } else {
            asm volatile("s_waitcnt vmcnt(0)" ::: "memory");  // last tile
        }
        __builtin_amdgcn_s_barrier();        // all waves: tile-k0 data present,
        asm volatile("" ::: "memory");       // tile-(k0-32) compute finished

        if (k0 + 64 < K) {
            const int nb = (cur + 2 >= 3) ? cur - 1 : cur + 2;
            STAGE128(k0 + 64, nb);           // overwrites tile k0-32 (safe)
        }

        short8 af[4], wf[4];
#pragma unroll
        for (int mt = 0; mt < 4; ++mt)
            af[mt] = *(const short8*)&sm.st.A[cur][(wm * 64 + mt * 16 + lanelo) * 32 + quad * 8];
#pragma unroll
        for (int nt = 0; nt < 4; ++nt)
            wf[nt] = *(const short8*)&sm.st.W[cur][(wn * 64 + nt * 16 + lanelo) * 32 + quad * 8];
#pragma unroll
        for (int mt = 0; mt < 4; ++mt)
#pragma unroll
            for (int nt = 0; nt < 4; ++nt)
                acc[mt][nt] = MFMA_B16(af[mt], wf[nt], acc[mt][nt]);

        asm volatile("" ::: "memory");
        cur = (cur + 1 == 3) ? 0 : cur + 1;
    }
#undef STAGE128

    if (g.mode != 1) {
#pragma unroll
        for (int mt = 0; mt < 4; ++mt) {
#pragma unroll
            for (int nt = 0; nt < 4; ++nt) {
                const int col = bn + wn * 64 + nt * 16 + lanelo;
                const float bs = g.bias[col];
#pragma unroll
                for (int r = 0; r < 4; ++r) {
                    const int row = bm + wm * 64 + mt * 16 + quad * 4 + r;
                    const float val = (acc[mt][nt][r] + bs) * g.scale;
                    if (g.mode == 2)
                        ((float*)g.out)[(size_t)row * K + col] = val;
                    else
                        ((unsigned short*)g.out)[(size_t)row * K + col] = f2bf(val);
                }
            }
        }
    } else {
        __syncthreads();   // staging reads done before Lt (aliases st) is written
#pragma unroll
        for (int mt = 0; mt < 4; ++mt) {
#pragma unroll
            for (int nt = 0; nt < 4; ++nt) {
                const int nl = wn * 64 + nt * 16 + lanelo;
                const float bs = g.bias[bn + nl];
                short4_t pk;
#pragma unroll
                for (int r = 0; r < 4; ++r) pk[r] = (short)f2bf(acc[mt][nt][r] + bs);
                *(short4_t*)&sm.Lt[nl * 136 + wm * 64 + mt * 16 + quad * 4] = pk;
            }
        }
        __syncthreads();
        const int dl = t >> 1;
        const int sb = (t & 1) * 64;
        const int bb = bm >> 11;
        const int s0 = bm & 2047;
        const int hb = bb * 16 + ((bn + dl) >> 6);
        const int dd = (bn + dl) & 63;
        unsigned short* dst = (unsigned short*)g.out +
            ((size_t)hb * 64 + dd) * 2048 + s0 + sb;
#pragma unroll
        for (int j = 0; j < 8; ++j)
            *(short8*)(dst + j * 8) = *(const short8*)&sm.Lt[dl * 136 + sb + j * 8];
    }
}

// -- flash attention: Q-split 4-wave, LDS K/V, swapped softmax, XCD remap ----
// Round-8 addition: XCD-aware bijective remap (512 blocks, 512%8==0).
// Default dispatch spreads the 16 qt-blocks of each head across all 8 XCDs,
// so every XCD streams ALL 32 heads' K/V (16MB) through its 4MB L2 -> the
// K/V loads are L3-latency class. Remap: physical lin%8=c takes work
// c*64+lin/8 -> XCD c owns heads [4c,4c+4) = 2MB K/V, fully L2-resident.
__global__ __launch_bounds__(256) void attn_flash(
    const unsigned short* __restrict__ Qs,
    const unsigned short* __restrict__ Ks,
    const unsigned short* __restrict__ Vt,
    unsigned short* __restrict__ Op)
{
    constexpr int S = 2048, D = 1024;
    __shared__ short Kb[2][64 * 64];   // [buf][key][d-swizzled]  8 KB each
    __shared__ short Vb[2][64 * 64];   // [buf][d][key-swizzled]  8 KB each
    __shared__ short Pl[4][32 * 72];   // per-wave P tile [32 q][64 key]

    const int tid    = threadIdx.x;
    const int lane   = tid & 63;
    const int wave   = tid >> 6;          // Q-split slot 0..3
    const int lanelo = lane & 15;
    const int quad   = lane >> 4;

    // XCD-chunked bijective remap: grid (16,32) -> XCD c owns heads [4c,4c+4)
    const unsigned lin = blockIdx.x + 16u * blockIdx.y;
    const unsigned wl  = (lin & 7u) * 64u + (lin >> 3);
    const int qt = (int)(wl & 15u);       // 0..15 (128 q-rows per block)
    const int bh = (int)(wl >> 4);        // 0..31
    const int b  = bh >> 4;
    const int h  = bh & 15;
    const size_t base = (size_t)b * S * D + (size_t)h * 64;
    const unsigned short* Vh = Vt + (size_t)bh * 64 * S;
    short* Plw = Pl[wave];
    const int qrow0 = qt * 128 + wave * 32;

    short8 aq[2][2];
#pragma unroll
    for (int mt = 0; mt < 2; ++mt)
#pragma unroll
        for (int ks = 0; ks < 2; ++ks)
            aq[mt][ks] = *(const short8*)(Qs + base +
                (size_t)(qrow0 + mt * 16 + lanelo) * D + ks * 32 + quad * 8);

    f32x4 oacc[2][4] = {};
    float lac[2] = {0.0f, 0.0f};          // per-lane partial l for q=mt*16+lanelo

    const int lr = lane >> 3;
    const int lc = (((lane & 7) ^ lr) * 8);
    const unsigned short* kg = Ks + base + (size_t)(wave * 16 + lr) * D + lc;
    const unsigned short* vg = Vh + (size_t)(wave * 16 + lr) * S + lc;

#pragma unroll
    for (int i = 0; i < 2; ++i) {
        load16_lds(kg + (size_t)(i * 8) * D, &Kb[0][(wave * 2 + i) * 512]);
        load16_lds(vg + (size_t)(i * 8) * S, &Vb[0][(wave * 2 + i) * 512]);
    }
    __syncthreads();

    int cur = 0;
    for (int kt = 0; kt < 32; ++kt) {
        if (kt < 31) {
            const unsigned short* kgn = kg + (size_t)(kt + 1) * 64 * D;
            const unsigned short* vgn = vg + (kt + 1) * 64;
#pragma unroll
            for (int i = 0; i < 2; ++i) {
                load16_lds(kgn + (size_t)(i * 8) * D, &Kb[cur ^ 1][(wave * 2 + i) * 512]);
                load16_lds(vgn + (size_t)(i * 8) * S, &Vb[cur ^ 1][(wave * 2 + i) * 512]);
            }
        }

        short8 kfr[2][4];
#pragma unroll
        for (int ks = 0; ks < 2; ++ks)
#pragma unroll
            for (int nk = 0; nk < 4; ++nk) {
                const int k = nk * 16 + lanelo;
                kfr[ks][nk] = *(const short8*)&Kb[cur][k * 64 +
                    ((ks * 32 + quad * 8) ^ ((k & 7) << 3))];
            }

        f32x4 sv[2][4] = {};
        __builtin_amdgcn_s_setprio(1);
#pragma unroll
        for (int ks = 0; ks < 2; ++ks)
#pragma unroll
            for (int mt = 0; mt < 2; ++mt)
#pragma unroll
                for (int nt = 0; nt < 4; ++nt)
                    sv[mt][nt] = MFMA_B16(kfr[ks][nt], aq[mt][ks], sv[mt][nt]);
        __builtin_amdgcn_s_setprio(0);

#pragma unroll
        for (int mt = 0; mt < 2; ++mt)
#pragma unroll
            for (int nt = 0; nt < 4; ++nt) {
                unsigned u[4];
#pragma unroll
                for (int r = 0; r < 4; ++r) {
                    const float p = exp2f(sv[mt][nt][r]);
                    const unsigned tr = __builtin_bit_cast(unsigned, p) & 0xFFFF0000u;
                    lac[mt] += __builtin_bit_cast(float, tr);
                    u[r] = tr;
                }
                u32x2 pk;
                pk[0] = __builtin_amdgcn_perm(u[1], u[0], 0x07060302u);
                pk[1] = __builtin_amdgcn_perm(u[3], u[2], 0x07060302u);
                *(u32x2*)&Plw[(mt * 16 + lanelo) * 72 + nt * 16 + quad * 4] = pk;
            }

        __builtin_amdgcn_wave_barrier();

        __builtin_amdgcn_s_setprio(1);
#pragma unroll
        for (int ks = 0; ks < 2; ++ks) {
            short8 vfr[4];
#pragma unroll
            for (int nt = 0; nt < 4; ++nt) {
                const int d = nt * 16 + lanelo;
                vfr[nt] = *(const short8*)&Vb[cur][d * 64 +
                    ((ks * 32 + quad * 8) ^ ((d & 7) << 3))];
            }
            short8 ap[2];
#pragma unroll
            for (int mt = 0; mt < 2; ++mt)
                ap[mt] = *(const short8*)&Plw[(mt * 16 + lanelo) * 72 + ks * 32 + quad * 8];
#pragma unroll
            for (int mt = 0; mt < 2; ++mt)
#pragma unroll
                for (int nt = 0; nt < 4; ++nt)
                    oacc[mt][nt] = MFMA_B16(ap[mt], vfr[nt], oacc[mt][nt]);
        }
        __builtin_amdgcn_s_setprio(0);

        if (kt < 31) {
            __syncthreads();
            cur ^= 1;
        }
    }

    float lfull[2];
#pragma unroll
    for (int mt = 0; mt < 2; ++mt) {
        float l = lac[mt];
        l += __shfl_xor(l, 16);
        l += __shfl_xor(l, 32);
        lfull[mt] = l;
    }

#pragma unroll
    for (int mt = 0; mt < 2; ++mt)
#pragma unroll
        for (int r = 0; r < 4; ++r) {
            const float inv = 1.0f / __shfl(lfull[mt], quad * 4 + r);
            const int row = qrow0 + mt * 16 + quad * 4 + r;
#pragma unroll
            for (int nt = 0; nt < 4; ++nt)
                Op[base + (size_t)row * D + nt * 16 + lanelo] = f2bf(oacc[mt][nt][r] * inv);
        }
}

extern "C" void kernel_launch(void* const* d_in, const int* in_sizes, int n_in,
                              void* d_out, int out_size, void* d_ws, size_t ws_size,
                              hipStream_t stream) {
    const float* q   = (const float*)d_in[0];
    const float* k   = (const float*)d_in[1];
    const float* v   = (const float*)d_in[2];
    const float* W_q = (const float*)d_in[3];
    const float* b_q = (const float*)d_in[4];
    const float* W_k = (const float*)d_in[5];
    const float* b_k = (const float*)d_in[6];
    const float* W_v = (const float*)d_in[7];
    const float* b_v = (const float*)d_in[8];
    const float* W_o = (const float*)d_in[9];
    const float* b_o = (const float*)d_in[10];

    constexpr size_t M4 = (size_t)4 * 1024 * 1024;
    constexpr size_t M1 = (size_t)1024 * 1024;

    unsigned short* ob   = (unsigned short*)d_out;
    unsigned short* qb16 = ob;                 // [0,4M)
    unsigned short* wq16 = ob + M4;            // [4M,5M)
    unsigned short* wk16 = ob + M4 + M1;       // [5M,6M)
    unsigned short* wv16 = ob + M4 + 2 * M1;   // [6M,7M)
    unsigned short* d0   = (unsigned short*)d_in[0];
    unsigned short* d1   = (unsigned short*)d_in[1];
    unsigned short* d2   = (unsigned short*)d_in[2];
    unsigned short* kb16 = d0;                 // k bf16 (q fp32 dead after cvtA)
    unsigned short* vb16 = d0 + M4;            // v bf16
    unsigned short* wo16 = (unsigned short*)d_in[3];  // W_o bf16 over W_q fp32
                                               // (dead after cvtA; cvtB is
                                               // stream-ordered after cvtA)
    unsigned short* Qst  = d1;                 // Q stage
    unsigned short* Kst  = d1 + M4;            // K stage
    unsigned short* Vts  = d2;                 // V^T stage
    unsigned short* Ob16 = d2 + M4;            // O stage
    float*          outp = (float*)d_out;

    const dim3 blk(256, 1, 1);
    const int n4 = (int)(M4 / 8), n1 = (int)(M1 / 8);
    const float QSCALE = 0.18033688f;    // 0.125 * log2(e)

    cvt5<<<dim3(2048, 4, 1), blk, 0, stream>>>(
        q, qb16, n4,  W_q, wq16, n1,  W_k, wk16, n1,  W_v, wv16, n1,
        (const float*)nullptr, (unsigned short*)nullptr, 0);
    cvt5<<<dim3(2048, 3, 1), blk, 0, stream>>>(
        k, kb16, n4,  v, vb16, n4,  W_o, wo16, n1,
        nullptr, nullptr, 0, nullptr, nullptr, 0);
    {
        GemmDesc gq{qb16, wq16, b_q, Qst, QSCALE, 0};
        GemmDesc gk{kb16, wk16, b_k, Kst, 1.0f, 0};
        GemmDesc gv{vb16, wv16, b_v, Vts, 1.0f, 1};
        gemm128<<<dim3(8, 32, 3), blk, 0, stream>>>(gq, gk, gv);
    }
    attn_flash<<<dim3(16, 32, 1), blk, 0, stream>>>(Qst, Kst, Vts, Ob16);
    {
        GemmDesc go{Ob16, wo16, b_o, outp, 1.0f, 2};
        gemm128<<<dim3(8, 32, 1), blk, 0, stream>>>(go, go, go);
    }
}

// Round 10
// 247.650 us; speedup vs baseline: 1.1058x; 1.0115x over previous
//
#include <hip/hip_runtime.h>

typedef __attribute__((ext_vector_type(8))) short short8;
typedef __attribute__((ext_vector_type(4))) short short4_t;
typedef __attribute__((ext_vector_type(4))) float f32x4;
typedef __attribute__((ext_vector_type(2))) unsigned int u32x2;

#define MFMA_B16(a, b, c) __builtin_amdgcn_mfma_f32_16x16x32_bf16((a), (b), (c), 0, 0, 0)

__device__ __forceinline__ unsigned short f2bf(float x) {
    unsigned u = __builtin_bit_cast(unsigned, x);
    u = (u + 0x7FFFu + ((u >> 16) & 1u)) >> 16;
    return (unsigned short)u;
}

__device__ __forceinline__ void load16_lds(const void* g, void* l) {
    __builtin_amdgcn_global_load_lds(
        (const __attribute__((address_space(1))) unsigned int*)g,
        (__attribute__((address_space(3))) unsigned int*)l, 16, 0, 0);
}

// ---------------- multi-tensor fp32 -> bf16 convert (8 elems/thread) --------
__global__ __launch_bounds__(256) void cvt5(
    const float* s0, unsigned short* d0, int n0,
    const float* s1, unsigned short* d1, int n1,
    const float* s2, unsigned short* d2, int n2,
    const float* s3, unsigned short* d3, int n3,
    const float* s4, unsigned short* d4, int n4)
{
    const float* s; unsigned short* d; int n;
    switch (blockIdx.y) {
        case 0:  s = s0; d = d0; n = n0; break;
        case 1:  s = s1; d = d1; n = n1; break;
        case 2:  s = s2; d = d2; n = n2; break;
        case 3:  s = s3; d = d3; n = n3; break;
        default: s = s4; d = d4; n = n4; break;
    }
    const int i = blockIdx.x * 256 + threadIdx.x;
    if (i < n) {
        const float* p = s + (size_t)i * 8;
        f32x4 x0 = *(const f32x4*)p;
        f32x4 x1 = *(const f32x4*)(p + 4);
        short8 r;
#pragma unroll
        for (int j = 0; j < 4; ++j) r[j] = (short)f2bf(x0[j]);
#pragma unroll
        for (int j = 0; j < 4; ++j) r[j + 4] = (short)f2bf(x1[j]);
        *(short8*)(d + (size_t)i * 8) = r;
    }
}

// -- NT GEMM: 128x128 tile, 3-ring counted-vmcnt, XCD-chunked block remap ----
// (unchanged from round 9, verified)
struct GemmDesc {
    const unsigned short* A;
    const unsigned short* W;
    const float* bias;
    void* out;
    float scale;
    int mode;   // 0 = bf16 row-major, 1 = V^T per-head [b][h][64][2048], 2 = fp32
};

__global__ __launch_bounds__(256) void gemm128(GemmDesc g0, GemmDesc g1, GemmDesc g2)
{
    constexpr int K = 1024;
    __shared__ union {
        struct { short A[3][128 * 32]; short W[3][128 * 32]; } st;  // 48 KB
        short Lt[128 * 136];                                        // 34.8 KB
    } sm;

    // XCD-chunked bijective remap (requires nwg % 8 == 0; 768 and 256 both ok)
    const unsigned nwg = gridDim.x * gridDim.y * gridDim.z;
    const unsigned lin = blockIdx.x + gridDim.x * (blockIdx.y + gridDim.y * blockIdx.z);
    const unsigned wl  = (lin & 7u) * (nwg >> 3) + (lin >> 3);
    const unsigned pxy = gridDim.x * gridDim.y;
    const unsigned bz  = wl / pxy;
    const unsigned rm  = wl - bz * pxy;
    const unsigned by  = rm / gridDim.x;
    const unsigned bx  = rm - by * gridDim.x;

    const GemmDesc g = (bz == 0) ? g0 : (bz == 1 ? g1 : g2);
    const int t = threadIdx.x;
    const int lane = t & 63, wave = t >> 6;
    const int lanelo = lane & 15, quad = lane >> 4;
    const int wm = wave >> 1, wn = wave & 1;
    const int bn = bx * 128;
    const int bm = by * 128;

    f32x4 acc[4][4] = {};

    const int r0 = t >> 2, c0 = (t & 3) * 8;
    const unsigned short* Ag = g.A + (size_t)(bm + r0) * K + c0;
    const unsigned short* Wg = g.W + (size_t)(bn + r0) * K + c0;

#define STAGE128(k0, buf)                                             \
    do {                                                              \
        short* la_ = sm.st.A[(buf)] + wave * 512;                     \
        short* lw_ = sm.st.W[(buf)] + wave * 512;                     \
        load16_lds(Ag + (k0), la_);                                   \
        load16_lds(Ag + (size_t)64 * K + (k0), la_ + 2048);           \
        load16_lds(Wg + (k0), lw_);                                   \
        load16_lds(Wg + (size_t)64 * K + (k0), lw_ + 2048);           \
    } while (0)

    // prologue: tiles 0 and 1 in flight
    STAGE128(0, 0);
    STAGE128(32, 1);

    int cur = 0;
    for (int k0 = 0; k0 < K; k0 += 32) {
        if (k0 + 32 < K) {
            asm volatile("s_waitcnt vmcnt(4)" ::: "memory");  // tile k0 landed
        } else {
            asm volatile("s_waitcnt vmcnt(0)" ::: "memory");  // last tile
        }
        __builtin_amdgcn_s_barrier();        // all waves: tile-k0 data present,
        asm volatile("" ::: "memory");       // tile-(k0-32) compute finished

        if (k0 + 64 < K) {
            const int nb = (cur + 2 >= 3) ? cur - 1 : cur + 2;
            STAGE128(k0 + 64, nb);           // overwrites tile k0-32 (safe)
        }

        short8 af[4], wf[4];
#pragma unroll
        for (int mt = 0; mt < 4; ++mt)
            af[mt] = *(const short8*)&sm.st.A[cur][(wm * 64 + mt * 16 + lanelo) * 32 + quad * 8];
#pragma unroll
        for (int nt = 0; nt < 4; ++nt)
            wf[nt] = *(const short8*)&sm.st.W[cur][(wn * 64 + nt * 16 + lanelo) * 32 + quad * 8];
#pragma unroll
        for (int mt = 0; mt < 4; ++mt)
#pragma unroll
            for (int nt = 0; nt < 4; ++nt)
                acc[mt][nt] = MFMA_B16(af[mt], wf[nt], acc[mt][nt]);

        asm volatile("" ::: "memory");
        cur = (cur + 1 == 3) ? 0 : cur + 1;
    }
#undef STAGE128

    if (g.mode != 1) {
#pragma unroll
        for (int mt = 0; mt < 4; ++mt) {
#pragma unroll
            for (int nt = 0; nt < 4; ++nt) {
                const int col = bn + wn * 64 + nt * 16 + lanelo;
                const float bs = g.bias[col];
#pragma unroll
                for (int r = 0; r < 4; ++r) {
                    const int row = bm + wm * 64 + mt * 16 + quad * 4 + r;
                    const float val = (acc[mt][nt][r] + bs) * g.scale;
                    if (g.mode == 2)
                        ((float*)g.out)[(size_t)row * K + col] = val;
                    else
                        ((unsigned short*)g.out)[(size_t)row * K + col] = f2bf(val);
                }
            }
        }
    } else {
        __syncthreads();   // staging reads done before Lt (aliases st) is written
#pragma unroll
        for (int mt = 0; mt < 4; ++mt) {
#pragma unroll
            for (int nt = 0; nt < 4; ++nt) {
                const int nl = wn * 64 + nt * 16 + lanelo;
                const float bs = g.bias[bn + nl];
                short4_t pk;
#pragma unroll
                for (int r = 0; r < 4; ++r) pk[r] = (short)f2bf(acc[mt][nt][r] + bs);
                *(short4_t*)&sm.Lt[nl * 136 + wm * 64 + mt * 16 + quad * 4] = pk;
            }
        }
        __syncthreads();
        const int dl = t >> 1;
        const int sb = (t & 1) * 64;
        const int bb = bm >> 11;
        const int s0 = bm & 2047;
        const int hb = bb * 16 + ((bn + dl) >> 6);
        const int dd = (bn + dl) & 63;
        unsigned short* dst = (unsigned short*)g.out +
            ((size_t)hb * 64 + dd) * 2048 + s0 + sb;
#pragma unroll
        for (int j = 0; j < 8; ++j)
            *(short8*)(dst + j * 8) = *(const short8*)&sm.Lt[dl * 136 + sb + j * 8];
    }
}

// -- flash attention: Q-split 4-wave, LDS K/V, swapped softmax, l via MFMA ---
// Round-9 post-mortem: XCD remap made K/V L2-resident (FETCH 70->12MB) but
// time was flat -> not latency-bound. VALUBusy 52% >> MfmaUtil 17%: VALU is
// the loaded pipe. Diet (this round): l is now computed ON THE MFMA PIPE as
// P @ ones -- one extra mfma(ap[mt], ones) per (mt,ks) reusing the ALREADY-
// LOADED packed-bf16 ap fragment. This (a) deletes the 32 AND-truncates and
// the two 16-deep serial lac+= chains per iter (l-consistency with P is now
// automatic: same operand), and (b) the ones-MFMA C-layout puts l[row] in
// lacc[mt][r] with EXACTLY oacc's per-lane alignment -> epilogue needs zero
// shuffles (was 4 shfl_xor + 1 shfl per row). +4 MFMAs/iter on a 17%-busy
// pipe. Everything else unchanged from round 9.
__global__ __launch_bounds__(256) void attn_flash(
    const unsigned short* __restrict__ Qs,
    const unsigned short* __restrict__ Ks,
    const unsigned short* __restrict__ Vt,
    unsigned short* __restrict__ Op)
{
    constexpr int S = 2048, D = 1024;
    __shared__ short Kb[2][64 * 64];   // [buf][key][d-swizzled]  8 KB each
    __shared__ short Vb[2][64 * 64];   // [buf][d][key-swizzled]  8 KB each
    __shared__ short Pl[4][32 * 72];   // per-wave P tile [32 q][64 key]

    const int tid    = threadIdx.x;
    const int lane   = tid & 63;
    const int wave   = tid >> 6;          // Q-split slot 0..3
    const int lanelo = lane & 15;
    const int quad   = lane >> 4;

    // XCD-chunked bijective remap: grid (16,32) -> XCD c owns heads [4c,4c+4)
    const unsigned lin = blockIdx.x + 16u * blockIdx.y;
    const unsigned wl  = (lin & 7u) * 64u + (lin >> 3);
    const int qt = (int)(wl & 15u);       // 0..15 (128 q-rows per block)
    const int bh = (int)(wl >> 4);        // 0..31
    const int b  = bh >> 4;
    const int h  = bh & 15;
    const size_t base = (size_t)b * S * D + (size_t)h * 64;
    const unsigned short* Vh = Vt + (size_t)bh * 64 * S;
    short* Plw = Pl[wave];
    const int qrow0 = qt * 128 + wave * 32;

    short8 aq[2][2];
#pragma unroll
    for (int mt = 0; mt < 2; ++mt)
#pragma unroll
        for (int ks = 0; ks < 2; ++ks)
            aq[mt][ks] = *(const short8*)(Qs + base +
                (size_t)(qrow0 + mt * 16 + lanelo) * D + ks * 32 + quad * 8);

    f32x4 oacc[2][4] = {};
    f32x4 lacc[2] = {};                   // l row-sums, accumulated by MFMA

    short8 ones8;
#pragma unroll
    for (int j = 0; j < 8; ++j) ones8[j] = (short)0x3F80;   // bf16 1.0

    const int lr = lane >> 3;
    const int lc = (((lane & 7) ^ lr) * 8);
    const unsigned short* kg = Ks + base + (size_t)(wave * 16 + lr) * D + lc;
    const unsigned short* vg = Vh + (size_t)(wave * 16 + lr) * S + lc;

#pragma unroll
    for (int i = 0; i < 2; ++i) {
        load16_lds(kg + (size_t)(i * 8) * D, &Kb[0][(wave * 2 + i) * 512]);
        load16_lds(vg + (size_t)(i * 8) * S, &Vb[0][(wave * 2 + i) * 512]);
    }
    __syncthreads();

    int cur = 0;
    for (int kt = 0; kt < 32; ++kt) {
        if (kt < 31) {
            const unsigned short* kgn = kg + (size_t)(kt + 1) * 64 * D;
            const unsigned short* vgn = vg + (kt + 1) * 64;
#pragma unroll
            for (int i = 0; i < 2; ++i) {
                load16_lds(kgn + (size_t)(i * 8) * D, &Kb[cur ^ 1][(wave * 2 + i) * 512]);
                load16_lds(vgn + (size_t)(i * 8) * S, &Vb[cur ^ 1][(wave * 2 + i) * 512]);
            }
        }

        short8 kfr[2][4];
#pragma unroll
        for (int ks = 0; ks < 2; ++ks)
#pragma unroll
            for (int nk = 0; nk < 4; ++nk) {
                const int k = nk * 16 + lanelo;
                kfr[ks][nk] = *(const short8*)&Kb[cur][k * 64 +
                    ((ks * 32 + quad * 8) ^ ((k & 7) << 3))];
            }

        f32x4 sv[2][4] = {};
        __builtin_amdgcn_s_setprio(1);
#pragma unroll
        for (int ks = 0; ks < 2; ++ks)
#pragma unroll
            for (int mt = 0; mt < 2; ++mt)
#pragma unroll
                for (int nt = 0; nt < 4; ++nt)
                    sv[mt][nt] = MFMA_B16(kfr[ks][nt], aq[mt][ks], sv[mt][nt]);
        __builtin_amdgcn_s_setprio(0);

        // p = exp2(s); pack 4 consecutive keys -> one ds_write_b64. The perm
        // selects the high 2 bytes of each f32 (= bf16 truncation); no
        // separate AND / l accumulation -- l comes from the ones-MFMA below,
        // reading the SAME packed values (consistency automatic).
#pragma unroll
        for (int mt = 0; mt < 2; ++mt)
#pragma unroll
            for (int nt = 0; nt < 4; ++nt) {
                unsigned u[4];
#pragma unroll
                for (int r = 0; r < 4; ++r)
                    u[r] = __builtin_bit_cast(unsigned, exp2f(sv[mt][nt][r]));
                u32x2 pk;
                pk[0] = __builtin_amdgcn_perm(u[1], u[0], 0x07060302u);
                pk[1] = __builtin_amdgcn_perm(u[3], u[2], 0x07060302u);
                *(u32x2*)&Plw[(mt * 16 + lanelo) * 72 + nt * 16 + quad * 4] = pk;
            }

        __builtin_amdgcn_wave_barrier();

        __builtin_amdgcn_s_setprio(1);
#pragma unroll
        for (int ks = 0; ks < 2; ++ks) {
            short8 vfr[4];
#pragma unroll
            for (int nt = 0; nt < 4; ++nt) {
                const int d = nt * 16 + lanelo;
                vfr[nt] = *(const short8*)&Vb[cur][d * 64 +
                    ((ks * 32 + quad * 8) ^ ((d & 7) << 3))];
            }
            short8 ap[2];
#pragma unroll
            for (int mt = 0; mt < 2; ++mt)
                ap[mt] = *(const short8*)&Plw[(mt * 16 + lanelo) * 72 + ks * 32 + quad * 8];
#pragma unroll
            for (int mt = 0; mt < 2; ++mt) {
                lacc[mt] = MFMA_B16(ap[mt], ones8, lacc[mt]);   // l += P row-sums
#pragma unroll
                for (int nt = 0; nt < 4; ++nt)
                    oacc[mt][nt] = MFMA_B16(ap[mt], vfr[nt], oacc[mt][nt]);
            }
        }
        __builtin_amdgcn_s_setprio(0);

        if (kt < 31) {
            __syncthreads();
            cur ^= 1;
        }
    }

    // ---- epilogue: lacc[mt][r] is l[qrow0+mt*16+quad*4+r] -- exactly the
    // per-lane alignment of oacc[mt][nt][r]; no cross-lane ops needed.
#pragma unroll
    for (int mt = 0; mt < 2; ++mt)
#pragma unroll
        for (int r = 0; r < 4; ++r) {
            const float inv = 1.0f / lacc[mt][r];
            const int row = qrow0 + mt * 16 + quad * 4 + r;
#pragma unroll
            for (int nt = 0; nt < 4; ++nt)
                Op[base + (size_t)row * D + nt * 16 + lanelo] = f2bf(oacc[mt][nt][r] * inv);
        }
}

extern "C" void kernel_launch(void* const* d_in, const int* in_sizes, int n_in,
                              void* d_out, int out_size, void* d_ws, size_t ws_size,
                              hipStream_t stream) {
    const float* q   = (const float*)d_in[0];
    const float* k   = (const float*)d_in[1];
    const float* v   = (const float*)d_in[2];
    const float* W_q = (const float*)d_in[3];
    const float* b_q = (const float*)d_in[4];
    const float* W_k = (const float*)d_in[5];
    const float* b_k = (const float*)d_in[6];
    const float* W_v = (const float*)d_in[7];
    const float* b_v = (const float*)d_in[8];
    const float* W_o = (const float*)d_in[9];
    const float* b_o = (const float*)d_in[10];

    constexpr size_t M4 = (size_t)4 * 1024 * 1024;
    constexpr size_t M1 = (size_t)1024 * 1024;

    unsigned short* ob   = (unsigned short*)d_out;
    unsigned short* qb16 = ob;                 // [0,4M)
    unsigned short* wq16 = ob + M4;            // [4M,5M)
    unsigned short* wk16 = ob + M4 + M1;       // [5M,6M)
    unsigned short* wv16 = ob + M4 + 2 * M1;   // [6M,7M)
    unsigned short* d0   = (unsigned short*)d_in[0];
    unsigned short* d1   = (unsigned short*)d_in[1];
    unsigned short* d2   = (unsigned short*)d_in[2];
    unsigned short* kb16 = d0;                 // k bf16 (q fp32 dead after cvtA)
    unsigned short* vb16 = d0 + M4;            // v bf16
    unsigned short* wo16 = (unsigned short*)d_in[3];  // W_o bf16 over W_q fp32
                                               // (dead after cvtA; cvtB is
                                               // stream-ordered after cvtA)
    unsigned short* Qst  = d1;                 // Q stage
    unsigned short* Kst  = d1 + M4;            // K stage
    unsigned short* Vts  = d2;                 // V^T stage
    unsigned short* Ob16 = d2 + M4;            // O stage
    float*          outp = (float*)d_out;

    const dim3 blk(256, 1, 1);
    const int n4 = (int)(M4 / 8), n1 = (int)(M1 / 8);
    const float QSCALE = 0.18033688f;    // 0.125 * log2(e)

    cvt5<<<dim3(2048, 4, 1), blk, 0, stream>>>(
        q, qb16, n4,  W_q, wq16, n1,  W_k, wk16, n1,  W_v, wv16, n1,
        (const float*)nullptr, (unsigned short*)nullptr, 0);
    cvt5<<<dim3(2048, 3, 1), blk, 0, stream>>>(
        k, kb16, n4,  v, vb16, n4,  W_o, wo16, n1,
        nullptr, nullptr, 0, nullptr, nullptr, 0);
    {
        GemmDesc gq{qb16, wq16, b_q, Qst, QSCALE, 0};
        GemmDesc gk{kb16, wk16, b_k, Kst, 1.0f, 0};
        GemmDesc gv{vb16, wv16, b_v, Vts, 1.0f, 1};
        gemm128<<<dim3(8, 32, 3), blk, 0, stream>>>(gq, gk, gv);
    }
    attn_flash<<<dim3(16, 32, 1), blk, 0, stream>>>(Qst, Kst, Vts, Ob16);
    {
        GemmDesc go{Ob16, wo16, b_o, outp, 1.0f, 2};
        gemm128<<<dim3(8, 32, 1), blk, 0, stream>>>(go, go, go);
    }
}